// Round 19
// baseline (112.629 us; speedup 1.0000x reference)
//
#include <hip/hip_runtime.h>
#include <hip/hip_bf16.h>
#include <stdint.h>

// MHA: B=8, N=1024, DIM=768, H=12, D=64.  I/O fp32; internal bf16 MFMA.
#define NH 12

typedef __attribute__((ext_vector_type(8))) short bf16x8;
typedef __attribute__((ext_vector_type(4))) float f32x4;

static __device__ __forceinline__ ushort f2bf(float f) {
  union { float f; uint32_t u; } v; v.f = f;
  uint32_t r = (v.u + 0x7FFFu + ((v.u >> 16) & 1u)) >> 16;
  return (ushort)r;
}

static __device__ __forceinline__ uint32_t cvtpk(float lo, float hi) {
  uint32_t r;
  asm("v_cvt_pk_bf16_f32 %0, %1, %2" : "=v"(r) : "v"(lo), "v"(hi));
  return r;
}

static __device__ __forceinline__ void gl_lds16(const void* g, void* l) {
  __builtin_amdgcn_global_load_lds(
      (const __attribute__((address_space(1))) uint32_t*)(uintptr_t)g,
      (__attribute__((address_space(3))) uint32_t*)(uintptr_t)l,
      16, 0, 0);
}

static __device__ __forceinline__ f32x4 mfma32(bf16x8 a, bf16x8 b, f32x4 c) {
  return __builtin_amdgcn_mfma_f32_16x16x32_bf16(a, b, c, 0, 0, 0);
}

// Q pre-scale: 1/sqrt(64) * log2(e)  (softmax runs in exp2 domain)
#define QSCALE 0.1803368801111601f

// ---------------- fused converts (one launch) ----------------------------
#define N4_X  1572864
#define N4_WQ 442368
#define N4_WP 147456
__global__ __launch_bounds__(256) void k_cvt_all(const float4* __restrict__ X,
                                                 const float4* __restrict__ Wq,
                                                 const float4* __restrict__ Wp,
                                                 ushort4* __restrict__ Xb,
                                                 ushort4* __restrict__ Wqb,
                                                 ushort4* __restrict__ Wpb) {
  int i = blockIdx.x * 256 + threadIdx.x;
  if (i < N4_X) {
    float4 v = X[i];
    ushort4 o;
    o.x = f2bf(v.x); o.y = f2bf(v.y); o.z = f2bf(v.z); o.w = f2bf(v.w);
    Xb[i] = o;
  } else if (i < N4_X + N4_WQ) {
    int j = i - N4_X;                     // 2304 rows * 192 chunks
    int ro = j / 192, cc = j - ro * 192;
    int h = ro / 192;
    int rem = ro - h * 192;
    int d = rem / 3;
    int which = rem - d * 3;
    int rn = which * 768 + h * 64 + d;
    float4 v = Wq[j];
    ushort4 o;
    o.x = f2bf(v.x); o.y = f2bf(v.y); o.z = f2bf(v.z); o.w = f2bf(v.w);
    Wqb[(size_t)rn * 192 + cc] = o;
  } else {
    int j = i - N4_X - N4_WQ;
    float4 v = Wp[j];
    ushort4 o;
    o.x = f2bf(v.x); o.y = f2bf(v.y); o.z = f2bf(v.z); o.w = f2bf(v.w);
    Wpb[j] = o;
  }
}

// ---------------- sync primitives ----------------------------------------
#define WB4 do { __builtin_amdgcn_sched_barrier(0); \
    asm volatile("s_waitcnt vmcnt(4)\n\ts_barrier" ::: "memory"); \
    __builtin_amdgcn_sched_barrier(0); } while (0)
#define WB3 do { __builtin_amdgcn_sched_barrier(0); \
    asm volatile("s_waitcnt vmcnt(3)\n\ts_barrier" ::: "memory"); \
    __builtin_amdgcn_sched_barrier(0); } while (0)
#define WB0 do { __builtin_amdgcn_sched_barrier(0); \
    asm volatile("s_waitcnt vmcnt(0)\n\ts_barrier" ::: "memory"); \
    __builtin_amdgcn_sched_barrier(0); } while (0)
#define PFENCE do { asm volatile("" ::: "memory"); \
    __builtin_amdgcn_sched_barrier(0); } while (0)

// ---------------- Kernel 1: QKV projection (r17 + T5 setprio) ------------
__global__ __launch_bounds__(512, 2) void k_qkv(const ushort* __restrict__ X,
                                                const ushort* __restrict__ W,
                                                ushort* __restrict__ Qb,
                                                ushort* __restrict__ Kf,
                                                ushort* __restrict__ Vf) {
  __shared__ __align__(16) ushort lds[36864];   // 72KB: 3x16KB A + 3x8KB B
  const int id = (int)blockIdx.x;               // 576 blocks, %8==0
  const int swz = (id & 7) * 72 + (id >> 3);
  const int bx = swz % 18, by = swz / 18;       // by 0..31
  const int m0 = by * 256, n0 = bx * 128;
  const int tid = threadIdx.x;                  // 0..511
  const int w = tid >> 6, l = tid & 63, g = l >> 4, c15 = l & 15;
  const int rowA = tid >> 2;                    // 0..127
  const int cgA = ((tid & 3) ^ ((tid >> 3) & 3)) * 8;
  const int gsw = (g ^ ((c15 >> 1) & 3)) * 8;

#define A_BUF(i) ((char*)lds + (i) * 16384)
#define B_BUF(i) ((char*)lds + 49152 + (i) * 8192)

#define STAGE8(bi, kk0) do { \
    gl_lds16(X + (size_t)(m0 + rowA) * 768 + (kk0) + cgA, A_BUF(bi) + tid * 16); \
    gl_lds16(X + (size_t)(m0 + rowA + 128) * 768 + (kk0) + cgA, A_BUF(bi) + tid * 16 + 8192); \
    gl_lds16(W + (size_t)(n0 + rowA) * 768 + (kk0) + cgA, B_BUF(bi) + tid * 16); \
  } while (0)

#define COMPUTE8(bi) do { \
    const ushort* _a = (const ushort*)A_BUF(bi); \
    const ushort* _b = (const ushort*)B_BUF(bi); \
    bf16x8 af[2]; \
    _Pragma("unroll") \
    for (int i = 0; i < 2; i++) \
      af[i] = *(const bf16x8*)&_a[(w * 32 + i * 16 + c15) * 32 + gsw]; \
    _Pragma("unroll") \
    for (int half = 0; half < 2; half++) { \
      bf16x8 bfr[4]; \
      _Pragma("unroll") \
      for (int i = 0; i < 4; i++) \
        bfr[i] = *(const bf16x8*)&_b[((half * 4 + i) * 16 + c15) * 32 + gsw]; \
      __builtin_amdgcn_s_setprio(1); \
      _Pragma("unroll") \
      for (int mr = 0; mr < 2; mr++) \
        _Pragma("unroll") \
        for (int nr = 0; nr < 4; nr++) \
          acc[mr][half * 4 + nr] = mfma32(af[mr], bfr[nr], acc[mr][half * 4 + nr]); \
      __builtin_amdgcn_s_setprio(0); \
    } \
  } while (0)

  f32x4 acc[2][8] = {};

  STAGE8(0, 0);
  PFENCE;
  STAGE8(1, 32);
  WB3;                                    // confirms tile 0
#pragma unroll 1
  for (int p = 0; p < 21; p += 3) {
    STAGE8(2, (p + 2) * 32); COMPUTE8(0); WB3;   // confirms p+1
    STAGE8(0, (p + 3) * 32); COMPUTE8(1); WB3;   // confirms p+2
    STAGE8(1, (p + 4) * 32); COMPUTE8(2); WB3;   // confirms p+3
  }
  STAGE8(2, 736); COMPUTE8(0); WB3;       // confirms 22
  COMPUTE8(1); WB0;                       // confirms 23
  COMPUTE8(2);
  __syncthreads();                        // LDS reused as output image

  const int type = bx / 6;                 // 0=Q 1=K 2=V (uniform per block)
  const int cb = (bx % 6) * 128;
  const int h0 = cb >> 6;
  const int b = m0 >> 10, nbase = m0 & 1023, tbase = nbase >> 5;

  if (type == 0) {
#pragma unroll
    for (int nr = 0; nr < 8; nr++) {
      const int colrel = nr * 16 + c15;
#pragma unroll
      for (int mr = 0; mr < 2; mr++)
#pragma unroll
        for (int r = 0; r < 4; r++) {
          const int mrel = w * 32 + mr * 16 + 4 * g + r;
          lds[mrel * 128 + colrel] = f2bf(acc[mr][nr][r] * QSCALE);
        }
    }
    __syncthreads();
#pragma unroll
    for (int j = 0; j < 8; j++) {
      const int cid = j * 512 + tid;
      const int n = cid >> 4, coloff = (cid & 15) * 8;
      const int hrel = coloff >> 6, d0q = coloff & 63;
      bf16x8 vv = *(const bf16x8*)&lds[n * 128 + coloff];
      *(bf16x8*)(Qb + ((size_t)(b * NH + h0 + hrel) * 1024 + nbase + n) * 64 + d0q) = vv;
    }
  } else if (type == 1) {
#pragma unroll
    for (int nr = 0; nr < 8; nr++) {
      const int colrel = nr * 16 + c15;
      const int hrel = colrel >> 6, d = colrel & 63;
      const int gk = (d >> 3) & 3, ek = d & 7, hi = d >> 5;
#pragma unroll
      for (int mr = 0; mr < 2; mr++)
#pragma unroll
        for (int r = 0; r < 4; r++) {
          const int mrel = w * 32 + mr * 16 + 4 * g + r;
          const int trel = mrel >> 5, kk = mrel & 31;
          const int x = kk >> 3, s = (kk >> 2) & 1, y = kk & 3;
          lds[(hrel * 8 + trel) * 2048 + (2 * s + hi) * 512 +
              (gk * 16 + x * 4 + y) * 8 + ek] = f2bf(acc[mr][nr][r]);
        }
    }
    __syncthreads();
    const int c = tid >> 5, jj = tid & 31;   // c 0..15
    ushort* dst = Kf + ((size_t)(b * NH + h0 + (c >> 3)) * 32 + tbase + (c & 7)) * 2048;
    const ushort* srcl = lds + c * 2048;
#pragma unroll
    for (int k2 = 0; k2 < 8; k2++)
      *(bf16x8*)(dst + jj * 8 + k2 * 256) = *(const bf16x8*)(srcl + jj * 8 + k2 * 256);
  } else {
#pragma unroll
    for (int nr = 0; nr < 8; nr++) {
      const int colrel = nr * 16 + c15;
      const int hrel = colrel >> 6, d = colrel & 63;
      const int dtv = d >> 4, cv = d & 15;
#pragma unroll
      for (int mr = 0; mr < 2; mr++)
#pragma unroll
        for (int r = 0; r < 4; r++) {
          const int mrel = w * 32 + mr * 16 + 4 * g + r;
          const int trel = mrel >> 5, kk = mrel & 31;
          const int gv = kk >> 3, ev = kk & 7;
          lds[(hrel * 8 + trel) * 2048 + dtv * 512 +
              (gv * 16 + cv) * 8 + ev] = f2bf(acc[mr][nr][r]);
        }
    }
    __syncthreads();
    const int c = tid >> 5, jj = tid & 31;
    ushort* dst = Vf + ((size_t)(b * NH + h0 + (c >> 3)) * 32 + tbase + (c & 7)) * 2048;
    const ushort* srcl = lds + c * 2048;
#pragma unroll
    for (int k2 = 0; k2 < 8; k2++)
      *(bf16x8*)(dst + jj * 8 + k2 * 256) = *(const bf16x8*)(srcl + jj * 8 + k2 * 256);
  }
#undef STAGE8
#undef COMPUTE8
#undef A_BUF
#undef B_BUF
}

// ---------------- Kernel 2: flash attention, KVBLK=64 + T5 setprio -------
__global__ __launch_bounds__(256, 3) void k_attn(const ushort* __restrict__ Qb,
                                                 const ushort* __restrict__ Kf,
                                                 const ushort* __restrict__ Vf,
                                                 ushort* __restrict__ Ab) {
  __shared__ __align__(16) ushort kv[3][8192];  // [K0 2K|V0 2K|K1 2K|V1 2K]
  const int bh = blockIdx.x;
  const int tid = threadIdx.x;
  const int w = tid >> 6, l = tid & 63, g = l >> 4, c15 = l & 15;
  const int q0 = blockIdx.y * 128 + w * 32;

  bf16x8 qf0a, qf0b, qf1a, qf1b;
  {
    const ushort* qp = Qb + ((size_t)bh * 1024 + q0 + c15) * 64 + g * 8;
    qf0a = *(const bf16x8*)qp;
    qf0b = *(const bf16x8*)(qp + 32);
    qf1a = *(const bf16x8*)(qp + 1024);        // q + 16 rows
    qf1b = *(const bf16x8*)(qp + 1024 + 32);
  }
  const ushort* kgb = Kf + (size_t)bh * 32 * 2048;
  const ushort* vgb = Vf + (size_t)bh * 32 * 2048;

  bf16x8 vones;
#pragma unroll
  for (int j = 0; j < 8; j++) vones[j] = (short)0x3F80;  // bf16 1.0

  f32x4 o0[4] = {}, o1[4] = {};
  f32x4 ol0 = {}, ol1 = {};   // row-sum accumulators (denominator)

#define STAGE_KV2(bi, t2) do { \
    const size_t _o = (size_t)(t2) * 4096; \
    gl_lds16(kgb + _o + tid * 8,        (char*)kv[bi] + tid * 16); \
    gl_lds16(vgb + _o + tid * 8,        (char*)kv[bi] + 4096 + tid * 16); \
    gl_lds16(kgb + _o + 2048 + tid * 8, (char*)kv[bi] + 8192 + tid * 16); \
    gl_lds16(vgb + _o + 2048 + tid * 8, (char*)kv[bi] + 12288 + tid * 16); \
  } while (0)

#define ATT_HALF(basek) do { \
    const ushort* kp = (basek) + l * 8; \
    const ushort* vp = (basek) + 2048 + l * 8; \
    bf16x8 ka0a = *(const bf16x8*)(kp); \
    bf16x8 ka0b = *(const bf16x8*)(kp + 512); \
    bf16x8 ka1a = *(const bf16x8*)(kp + 1024); \
    bf16x8 ka1b = *(const bf16x8*)(kp + 1536); \
    f32x4 s00 = {0.f,0.f,0.f,0.f}, s01 = {0.f,0.f,0.f,0.f}; \
    f32x4 s10 = {0.f,0.f,0.f,0.f}, s11 = {0.f,0.f,0.f,0.f}; \
    __builtin_amdgcn_s_setprio(1); \
    s00 = mfma32(ka0a, qf0a, s00); s00 = mfma32(ka0b, qf0b, s00); \
    s01 = mfma32(ka0a, qf1a, s01); s01 = mfma32(ka0b, qf1b, s01); \
    s10 = mfma32(ka1a, qf0a, s10); s10 = mfma32(ka1b, qf0b, s10); \
    s11 = mfma32(ka1a, qf1a, s11); s11 = mfma32(ka1b, qf1b, s11); \
    __builtin_amdgcn_s_setprio(0); \
    float p0[8], p1[8]; \
    _Pragma("unroll") \
    for (int r = 0; r < 4; r++) { \
      p0[r]     = exp2f(s00[r]); \
      p0[4 + r] = exp2f(s10[r]); \
      p1[r]     = exp2f(s01[r]); \
      p1[4 + r] = exp2f(s11[r]); \
    } \
    union { uint32_t u[4]; bf16x8 v; } pa0, pa1; \
    _Pragma("unroll") \
    for (int j = 0; j < 4; j++) { \
      pa0.u[j] = cvtpk(p0[2 * j], p0[2 * j + 1]); \
      pa1.u[j] = cvtpk(p1[2 * j], p1[2 * j + 1]); \
    } \
    __builtin_amdgcn_s_setprio(1); \
    ol0 = mfma32(pa0.v, vones, ol0); \
    ol1 = mfma32(pa1.v, vones, ol1); \
    _Pragma("unroll") \
    for (int dt = 0; dt < 4; dt++) { \
      bf16x8 vb = *(const bf16x8*)(vp + dt * 512); \
      o0[dt] = mfma32(pa0.v, vb, o0[dt]); \
      o1[dt] = mfma32(pa1.v, vb, o1[dt]); \
    } \
    __builtin_amdgcn_s_setprio(0); \
  } while (0)

#define ATT_BODY2(bi) do { ATT_HALF(kv[bi]); ATT_HALF(kv[bi] + 4096); } while (0)

  STAGE_KV2(0, 0);
  PFENCE;
  STAGE_KV2(1, 1);
  WB4;                                   // confirms phase 0
#pragma unroll 1
  for (int t = 0; t < 12; t += 3) {
    STAGE_KV2(2, t + 2); ATT_BODY2(0); WB4;   // confirms t+1
    STAGE_KV2(0, t + 3); ATT_BODY2(1); WB4;   // confirms t+2
    STAGE_KV2(1, t + 4); ATT_BODY2(2); WB4;   // confirms t+3
  }
  STAGE_KV2(2, 14); ATT_BODY2(0); WB4;       // confirms 13
  STAGE_KV2(0, 15); ATT_BODY2(1); WB4;       // confirms 14
  ATT_BODY2(2); WB0;                         // confirms 15
  ATT_BODY2(0);
#undef ATT_BODY2
#undef ATT_HALF
#undef STAGE_KV2

  float il0[4], il1[4];
#pragma unroll
  for (int r = 0; r < 4; r++) {
    il0[r] = __builtin_amdgcn_rcpf(ol0[r]);
    il1[r] = __builtin_amdgcn_rcpf(ol1[r]);
  }
  const int b = bh / NH, h = bh % NH;
#pragma unroll
  for (int dt = 0; dt < 4; dt++)
#pragma unroll
    for (int r = 0; r < 4; r++) {
      const int n = q0 + 4 * g + r;
      Ab[(size_t)(b * 1024 + n) * 768 + h * 64 + dt * 16 + c15] =
          f2bf(o0[dt][r] * il0[r]);
      Ab[(size_t)(b * 1024 + n + 16) * 768 + h * 64 + dt * 16 + c15] =
          f2bf(o1[dt][r] * il1[r]);
    }
}

// ---------------- Kernel 3: output projection (r13 + T5 setprio) ---------
#define DECL_GEMM_VARS() \
  const int tid = threadIdx.x; \
  const int w = tid >> 6, l = tid & 63, g = l >> 4, c15 = l & 15; \
  const int wm = w >> 1, wn = w & 1; \
  const int dst0 = w * 1024 + l * 16; \
  const int row_s = w * 16 + (l >> 2); \
  const int cg = ((l & 3) ^ ((l >> 3) & 3)) * 8; \
  const int gsw = (g ^ ((c15 >> 1) & 3)) * 8;

#define STAGE(pa, pb, Aptr, Bptr, kk0) do { \
    gl_lds16((Aptr) + (size_t)(m0 + row_s) * 768 + (kk0) + cg, (char*)(pa) + dst0); \
    gl_lds16((Aptr) + (size_t)(m0 + row_s + 64) * 768 + (kk0) + cg, (char*)(pa) + dst0 + 4096); \
    gl_lds16((Bptr) + (size_t)(n0 + row_s) * 768 + (kk0) + cg, (char*)(pb) + dst0); \
    gl_lds16((Bptr) + (size_t)(n0 + row_s + 64) * 768 + (kk0) + cg, (char*)(pb) + dst0 + 4096); \
  } while (0)

#define COMPUTE(pa, pb) do { \
    bf16x8 af[4], bfr[4]; \
    _Pragma("unroll") \
    for (int i = 0; i < 4; i++) { \
      af[i]  = *(const bf16x8*)&(pa)[(wm * 64 + i * 16 + c15) * 32 + gsw]; \
      bfr[i] = *(const bf16x8*)&(pb)[(wn * 64 + i * 16 + c15) * 32 + gsw]; \
    } \
    __builtin_amdgcn_s_setprio(1); \
    _Pragma("unroll") \
    for (int mr = 0; mr < 4; mr++) \
      _Pragma("unroll") \
      for (int nr = 0; nr < 4; nr++) \
        acc[mr][nr] = mfma32(af[mr], bfr[nr], acc[mr][nr]); \
    __builtin_amdgcn_s_setprio(0); \
  } while (0)

#define GEMM_PIPE(Aptr, Bptr) do { \
    STAGE(A0, B0, Aptr, Bptr, 0); \
    PFENCE; \
    STAGE(A1, B1, Aptr, Bptr, 32); \
    WB4; \
    _Pragma("unroll 1") \
    for (int k0 = 0; k0 < 672; k0 += 96) { \
      STAGE(A2, B2, Aptr, Bptr, k0 + 64);  COMPUTE(A0, B0); WB4; \
      STAGE(A0, B0, Aptr, Bptr, k0 + 96);  COMPUTE(A1, B1); WB4; \
      STAGE(A1, B1, Aptr, Bptr, k0 + 128); COMPUTE(A2, B2); WB4; \
    } \
    STAGE(A2, B2, Aptr, Bptr, 736); COMPUTE(A0, B0); WB4; \
    COMPUTE(A1, B1); WB0; \
    COMPUTE(A2, B2); \
  } while (0)

__global__ __launch_bounds__(256, 3) void k_proj(const ushort* __restrict__ Ain,
                                                 const ushort* __restrict__ W,
                                                 const float* __restrict__ Bp,
                                                 float* __restrict__ Out) {
  __shared__ __align__(16) ushort lds[24576];
  const int id = (int)blockIdx.x;          // 384 blocks, %8==0
  const int swz = (id & 7) * 48 + (id >> 3);
  const int bx = swz % 6, by = swz / 6;
  const int m0 = by * 128, n0 = bx * 128;
  DECL_GEMM_VARS();

  ushort* A0 = lds;
  ushort* A1 = lds + 4096;
  ushort* A2 = lds + 8192;
  ushort* B0 = lds + 12288;
  ushort* B1 = lds + 16384;
  ushort* B2 = lds + 20480;

  f32x4 acc[4][4] = {};
  GEMM_PIPE(Ain, W);

#pragma unroll
  for (int nr = 0; nr < 4; nr++) {
    const int cc = n0 + wn * 64 + nr * 16 + c15;
    const float bias = Bp[cc];
#pragma unroll
    for (int mr = 0; mr < 4; mr++) {
      const int mb = m0 + wm * 64 + mr * 16 + 4 * g;
#pragma unroll
      for (int r = 0; r < 4; r++) {
        const int m = mb + r;
        Out[(size_t)m * 768 + cc] = acc[mr][nr][r] + bias;
      }
    }
  }
}

extern "C" void kernel_launch(void* const* d_in, const int* in_sizes, int n_in,
                              void* d_out, int out_size, void* d_ws, size_t ws_size,
                              hipStream_t stream) {
  const float* X  = (const float*)d_in[0];   // [8,1024,768] fp32
  const float* Wq = (const float*)d_in[1];   // [2304,768] fp32
  const float* Wp = (const float*)d_in[2];   // [768,768] fp32
  const float* Bp = (const float*)d_in[3];   // [768] fp32
  float* Out = (float*)d_out;                // [8,1024,768] fp32

  char* ws = (char*)d_ws;
  const size_t SZ = (size_t)96 * 1024 * 64 * sizeof(ushort);  // 12.58 MB
  ushort* Qb  = (ushort*)(ws);            // [96][1024][64] (scaled by QSCALE)
  ushort* Kf  = (ushort*)(ws + SZ);       // [96][32][4][64][8] fragment order
  ushort* Vf  = (ushort*)(ws + 2 * SZ);   // [96][32][4][64][8] fragment order
  ushort* Ab  = (ushort*)(ws + 3 * SZ);   // [8192][768]
  ushort* Xb  = (ushort*)(ws + 4 * SZ);   // [8192][768] bf16 of X
  ushort* Wqb = (ushort*)(ws + 5 * SZ);                  // [2304][768] permuted
  ushort* Wpb = (ushort*)(ws + 5 * SZ + 2304 * 768 * 2); // [768][768]

  k_cvt_all<<<(N4_X + N4_WQ + N4_WP) / 256, 256, 0, stream>>>(
      (const float4*)X, (const float4*)Wq, (const float4*)Wp,
      (ushort4*)Xb, (ushort4*)Wqb, (ushort4*)Wpb);

  k_qkv<<<576, 512, 0, stream>>>(Xb, Wqb, Qb, Kf, Vf);
  k_attn<<<dim3(96, 8), 256, 0, stream>>>(Qb, Kf, Vf, Ab);
  k_proj<<<384, 256, 0, stream>>>(Ab, Wpb, Bp, Out);
}

// Round 20
// 108.373 us; speedup vs baseline: 1.0393x; 1.0393x over previous
//
#include <hip/hip_runtime.h>
#include <hip/hip_bf16.h>
#include <stdint.h>

// MHA: B=8, N=1024, DIM=768, H=12, D=64.  I/O fp32; internal bf16 MFMA.
// FINAL: exact round-13 configuration (best measured: 108.99 us).
#define NH 12

typedef __attribute__((ext_vector_type(8))) short bf16x8;
typedef __attribute__((ext_vector_type(4))) float f32x4;

static __device__ __forceinline__ ushort f2bf(float f) {
  union { float f; uint32_t u; } v; v.f = f;
  uint32_t r = (v.u + 0x7FFFu + ((v.u >> 16) & 1u)) >> 16;
  return (ushort)r;
}

static __device__ __forceinline__ uint32_t cvtpk(float lo, float hi) {
  uint32_t r;
  asm("v_cvt_pk_bf16_f32 %0, %1, %2" : "=v"(r) : "v"(lo), "v"(hi));
  return r;
}

static __device__ __forceinline__ void gl_lds16(const void* g, void* l) {
  __builtin_amdgcn_global_load_lds(
      (const __attribute__((address_space(1))) uint32_t*)(uintptr_t)g,
      (__attribute__((address_space(3))) uint32_t*)(uintptr_t)l,
      16, 0, 0);
}

static __device__ __forceinline__ f32x4 mfma32(bf16x8 a, bf16x8 b, f32x4 c) {
  return __builtin_amdgcn_mfma_f32_16x16x32_bf16(a, b, c, 0, 0, 0);
}

// Q pre-scale: 1/sqrt(64) * log2(e)  (softmax runs in exp2 domain)
#define QSCALE 0.1803368801111601f

// ---------------- fused converts (one launch) ----------------------------
#define N4_X  1572864
#define N4_WQ 442368
#define N4_WP 147456
__global__ __launch_bounds__(256) void k_cvt_all(const float4* __restrict__ X,
                                                 const float4* __restrict__ Wq,
                                                 const float4* __restrict__ Wp,
                                                 ushort4* __restrict__ Xb,
                                                 ushort4* __restrict__ Wqb,
                                                 ushort4* __restrict__ Wpb) {
  int i = blockIdx.x * 256 + threadIdx.x;
  if (i < N4_X) {
    float4 v = X[i];
    ushort4 o;
    o.x = f2bf(v.x); o.y = f2bf(v.y); o.z = f2bf(v.z); o.w = f2bf(v.w);
    Xb[i] = o;
  } else if (i < N4_X + N4_WQ) {
    int j = i - N4_X;                     // 2304 rows * 192 chunks
    int ro = j / 192, cc = j - ro * 192;
    int h = ro / 192;
    int rem = ro - h * 192;
    int d = rem / 3;
    int which = rem - d * 3;
    int rn = which * 768 + h * 64 + d;
    float4 v = Wq[j];
    ushort4 o;
    o.x = f2bf(v.x); o.y = f2bf(v.y); o.z = f2bf(v.z); o.w = f2bf(v.w);
    Wqb[(size_t)rn * 192 + cc] = o;
  } else {
    int j = i - N4_X - N4_WQ;
    float4 v = Wp[j];
    ushort4 o;
    o.x = f2bf(v.x); o.y = f2bf(v.y); o.z = f2bf(v.z); o.w = f2bf(v.w);
    Wpb[j] = o;
  }
}

// ---------------- shared GEMM machinery (128x128 tile, BK=32) ------------
// XOR-swizzled staging (T21); 3-deep pipeline (T3/T4); indivisible
// {vmcnt(N); s_barrier} phase boundary flanked by sched_barrier(0).
#define DECL_GEMM_VARS() \
  const int tid = threadIdx.x; \
  const int w = tid >> 6, l = tid & 63, g = l >> 4, c15 = l & 15; \
  const int wm = w >> 1, wn = w & 1; \
  const int dst0 = w * 1024 + l * 16; \
  const int row_s = w * 16 + (l >> 2); \
  const int cg = ((l & 3) ^ ((l >> 3) & 3)) * 8; \
  const int gsw = (g ^ ((c15 >> 1) & 3)) * 8;

#define STAGE(pa, pb, Aptr, Bptr, kk0) do { \
    gl_lds16((Aptr) + (size_t)(m0 + row_s) * 768 + (kk0) + cg, (char*)(pa) + dst0); \
    gl_lds16((Aptr) + (size_t)(m0 + row_s + 64) * 768 + (kk0) + cg, (char*)(pa) + dst0 + 4096); \
    gl_lds16((Bptr) + (size_t)(n0 + row_s) * 768 + (kk0) + cg, (char*)(pb) + dst0); \
    gl_lds16((Bptr) + (size_t)(n0 + row_s + 64) * 768 + (kk0) + cg, (char*)(pb) + dst0 + 4096); \
  } while (0)

#define COMPUTE(pa, pb) do { \
    bf16x8 af[4], bfr[4]; \
    _Pragma("unroll") \
    for (int i = 0; i < 4; i++) { \
      af[i]  = *(const bf16x8*)&(pa)[(wm * 64 + i * 16 + c15) * 32 + gsw]; \
      bfr[i] = *(const bf16x8*)&(pb)[(wn * 64 + i * 16 + c15) * 32 + gsw]; \
    } \
    _Pragma("unroll") \
    for (int mr = 0; mr < 4; mr++) \
      _Pragma("unroll") \
      for (int nr = 0; nr < 4; nr++) \
        acc[mr][nr] = mfma32(af[mr], bfr[nr], acc[mr][nr]); \
  } while (0)

#define WB4 do { __builtin_amdgcn_sched_barrier(0); \
    asm volatile("s_waitcnt vmcnt(4)\n\ts_barrier" ::: "memory"); \
    __builtin_amdgcn_sched_barrier(0); } while (0)
#define WB2 do { __builtin_amdgcn_sched_barrier(0); \
    asm volatile("s_waitcnt vmcnt(2)\n\ts_barrier" ::: "memory"); \
    __builtin_amdgcn_sched_barrier(0); } while (0)
#define WB0 do { __builtin_amdgcn_sched_barrier(0); \
    asm volatile("s_waitcnt vmcnt(0)\n\ts_barrier" ::: "memory"); \
    __builtin_amdgcn_sched_barrier(0); } while (0)
#define PFENCE do { asm volatile("" ::: "memory"); \
    __builtin_amdgcn_sched_barrier(0); } while (0)

// Full K=768 pipelined loop: 24 K-steps, 3 LDS buffers/operand.
#define GEMM_PIPE(Aptr, Bptr) do { \
    STAGE(A0, B0, Aptr, Bptr, 0); \
    PFENCE; \
    STAGE(A1, B1, Aptr, Bptr, 32); \
    WB4; \
    _Pragma("unroll 1") \
    for (int k0 = 0; k0 < 672; k0 += 96) { \
      STAGE(A2, B2, Aptr, Bptr, k0 + 64);  COMPUTE(A0, B0); WB4; \
      STAGE(A0, B0, Aptr, Bptr, k0 + 96);  COMPUTE(A1, B1); WB4; \
      STAGE(A1, B1, Aptr, Bptr, k0 + 128); COMPUTE(A2, B2); WB4; \
    } \
    STAGE(A2, B2, Aptr, Bptr, 736); COMPUTE(A0, B0); WB4; \
    COMPUTE(A1, B1); WB0; \
    COMPUTE(A2, B2); \
  } while (0)

// ---------------- Kernel 1: QKV projection -------------------------------
__global__ __launch_bounds__(256, 3) void k_qkv(const ushort* __restrict__ X,
                                                const ushort* __restrict__ W,
                                                ushort* __restrict__ Qb,
                                                ushort* __restrict__ Kf,
                                                ushort* __restrict__ Vf) {
  __shared__ __align__(16) ushort lds[24576];   // 48KB: 3x8KB A + 3x8KB B
  const int id = (int)blockIdx.x;               // 1152 blocks, %8==0
  const int swz = (id & 7) * 144 + (id >> 3);
  const int bx = swz % 18, by = swz / 18;
  const int m0 = by * 128, n0 = bx * 128;
  DECL_GEMM_VARS();

  ushort* A0 = lds;
  ushort* A1 = lds + 4096;
  ushort* A2 = lds + 8192;
  ushort* B0 = lds + 12288;
  ushort* B1 = lds + 16384;
  ushort* B2 = lds + 20480;

  f32x4 acc[4][4] = {};
  GEMM_PIPE(X, W);
  __syncthreads();   // LDS reused as output image below

  const int type = bx / 6;                 // 0=Q 1=K 2=V (uniform per block)
  const int cb = (bx % 6) * 128;
  const int h0 = cb >> 6;
  const int b = m0 >> 10, nbase = m0 & 1023, tbase = nbase >> 5;

  if (type == 0) {
    // Q image: [n(128)][hd(128)]; scale includes log2(e) for exp2 softmax
#pragma unroll
    for (int nr = 0; nr < 4; nr++) {
      const int colrel = wn * 64 + nr * 16 + c15;
#pragma unroll
      for (int mr = 0; mr < 4; mr++)
#pragma unroll
        for (int r = 0; r < 4; r++) {
          const int mrel = wm * 64 + mr * 16 + 4 * g + r;
          lds[mrel * 128 + colrel] = f2bf(acc[mr][nr][r] * QSCALE);
        }
    }
    __syncthreads();
#pragma unroll
    for (int j = 0; j < 8; j++) {
      const int cid = j * 256 + tid;
      const int n = cid >> 4, coloff = (cid & 15) * 8;
      const int hrel = coloff >> 6, d0q = coloff & 63;
      bf16x8 vv = *(const bf16x8*)&lds[n * 128 + coloff];
      *(bf16x8*)(Qb + ((size_t)(b * NH + h0 + hrel) * 1024 + nbase + n) * 64 + d0q) = vv;
    }
  } else if (type == 1) {
    // K fragment image: [hrel*4+trel][2048]
#pragma unroll
    for (int nr = 0; nr < 4; nr++) {
      const int colrel = wn * 64 + nr * 16 + c15;
      const int hrel = colrel >> 6, d = colrel & 63;
      const int gk = (d >> 3) & 3, ek = d & 7, hi = d >> 5;
#pragma unroll
      for (int mr = 0; mr < 4; mr++)
#pragma unroll
        for (int r = 0; r < 4; r++) {
          const int mrel = wm * 64 + mr * 16 + 4 * g + r;
          const int trel = mrel >> 5, kk = mrel & 31;
          const int x = kk >> 3, s = (kk >> 2) & 1, y = kk & 3;
          lds[(hrel * 4 + trel) * 2048 + (2 * s + hi) * 512 +
              (gk * 16 + x * 4 + y) * 8 + ek] = f2bf(acc[mr][nr][r]);
        }
    }
    __syncthreads();
    const int c = tid >> 5, jj = tid & 31;
    ushort* dst = Kf + ((size_t)(b * NH + h0 + (c >> 2)) * 32 + tbase + (c & 3)) * 2048;
    const ushort* srcl = lds + c * 2048;
#pragma unroll
    for (int k2 = 0; k2 < 8; k2++)
      *(bf16x8*)(dst + jj * 8 + k2 * 256) = *(const bf16x8*)(srcl + jj * 8 + k2 * 256);
  } else {
    // V fragment image: [hrel*4+trel][dt][lane][8]
#pragma unroll
    for (int nr = 0; nr < 4; nr++) {
      const int colrel = wn * 64 + nr * 16 + c15;
      const int hrel = colrel >> 6, d = colrel & 63;
      const int dtv = d >> 4, cv = d & 15;
#pragma unroll
      for (int mr = 0; mr < 4; mr++)
#pragma unroll
        for (int r = 0; r < 4; r++) {
          const int mrel = wm * 64 + mr * 16 + 4 * g + r;
          const int trel = mrel >> 5, kk = mrel & 31;
          const int gv = kk >> 3, ev = kk & 7;
          lds[(hrel * 4 + trel) * 2048 + dtv * 512 +
              (gv * 16 + cv) * 8 + ev] = f2bf(acc[mr][nr][r]);
        }
    }
    __syncthreads();
    const int c = tid >> 5, jj = tid & 31;
    ushort* dst = Vf + ((size_t)(b * NH + h0 + (c >> 2)) * 32 + tbase + (c & 3)) * 2048;
    const ushort* srcl = lds + c * 2048;
#pragma unroll
    for (int k2 = 0; k2 < 8; k2++)
      *(bf16x8*)(dst + jj * 8 + k2 * 256) = *(const bf16x8*)(srcl + jj * 8 + k2 * 256);
  }
}

// ---------------- Kernel 2: flash attention ------------------------------
// 3 KV buffers, STAGE(t+2) at phase top, {vmcnt(2); s_barrier} at phase
// end (confirms tile t+1, leaves newest stage in flight).
__global__ __launch_bounds__(256, 3) void k_attn(const ushort* __restrict__ Qb,
                                                 const ushort* __restrict__ Kf,
                                                 const ushort* __restrict__ Vf,
                                                 ushort* __restrict__ Ab) {
  __shared__ __align__(16) ushort kv[3][4096];  // per tile: [K 2048 | V 2048]
  const int bh = blockIdx.x;
  const int tid = threadIdx.x;
  const int w = tid >> 6, l = tid & 63, g = l >> 4, c15 = l & 15;
  const int q0 = blockIdx.y * 128 + w * 32;

  bf16x8 qf0a, qf0b, qf1a, qf1b;
  {
    const ushort* qp = Qb + ((size_t)bh * 1024 + q0 + c15) * 64 + g * 8;
    qf0a = *(const bf16x8*)qp;
    qf0b = *(const bf16x8*)(qp + 32);
    qf1a = *(const bf16x8*)(qp + 1024);        // q + 16 rows
    qf1b = *(const bf16x8*)(qp + 1024 + 32);
  }
  const ushort* kgb = Kf + (size_t)bh * 32 * 2048;
  const ushort* vgb = Vf + (size_t)bh * 32 * 2048;

  bf16x8 vones;
#pragma unroll
  for (int j = 0; j < 8; j++) vones[j] = (short)0x3F80;  // bf16 1.0

  f32x4 o0[4] = {}, o1[4] = {};
  f32x4 ol0 = {}, ol1 = {};   // row-sum accumulators (denominator)

#define STAGE_KV(bi, t) do { \
    gl_lds16(kgb + (size_t)(t) * 2048 + tid * 8, (char*)kv[bi] + tid * 16); \
    gl_lds16(vgb + (size_t)(t) * 2048 + tid * 8, (char*)kv[bi] + 4096 + tid * 16); \
  } while (0)

#define ATT_BODY(bi) do { \
    const ushort* kp = kv[bi] + l * 8; \
    const ushort* vp = kv[bi] + 2048 + l * 8; \
    bf16x8 ka0a = *(const bf16x8*)(kp); \
    bf16x8 ka0b = *(const bf16x8*)(kp + 512); \
    bf16x8 ka1a = *(const bf16x8*)(kp + 1024); \
    bf16x8 ka1b = *(const bf16x8*)(kp + 1536); \
    f32x4 s00 = {0.f,0.f,0.f,0.f}, s01 = {0.f,0.f,0.f,0.f}; \
    f32x4 s10 = {0.f,0.f,0.f,0.f}, s11 = {0.f,0.f,0.f,0.f}; \
    s00 = mfma32(ka0a, qf0a, s00); s00 = mfma32(ka0b, qf0b, s00); \
    s01 = mfma32(ka0a, qf1a, s01); s01 = mfma32(ka0b, qf1b, s01); \
    s10 = mfma32(ka1a, qf0a, s10); s10 = mfma32(ka1b, qf0b, s10); \
    s11 = mfma32(ka1a, qf1a, s11); s11 = mfma32(ka1b, qf1b, s11); \
    float p0[8], p1[8]; \
    _Pragma("unroll") \
    for (int r = 0; r < 4; r++) { \
      p0[r]     = exp2f(s00[r]); \
      p0[4 + r] = exp2f(s10[r]); \
      p1[r]     = exp2f(s01[r]); \
      p1[4 + r] = exp2f(s11[r]); \
    } \
    union { uint32_t u[4]; bf16x8 v; } pa0, pa1; \
    _Pragma("unroll") \
    for (int j = 0; j < 4; j++) { \
      pa0.u[j] = cvtpk(p0[2 * j], p0[2 * j + 1]); \
      pa1.u[j] = cvtpk(p1[2 * j], p1[2 * j + 1]); \
    } \
    ol0 = mfma32(pa0.v, vones, ol0); \
    ol1 = mfma32(pa1.v, vones, ol1); \
    _Pragma("unroll") \
    for (int dt = 0; dt < 4; dt++) { \
      bf16x8 vb = *(const bf16x8*)(vp + dt * 512); \
      o0[dt] = mfma32(pa0.v, vb, o0[dt]); \
      o1[dt] = mfma32(pa1.v, vb, o1[dt]); \
    } \
  } while (0)

  STAGE_KV(0, 0);
  PFENCE;
  STAGE_KV(1, 1);
  WB2;                                   // confirms tile 0
#pragma unroll 1
  for (int t = 0; t < 27; t += 3) {
    STAGE_KV(2, t + 2); ATT_BODY(0); WB2;   // confirms t+1
    STAGE_KV(0, t + 3); ATT_BODY(1); WB2;   // confirms t+2
    STAGE_KV(1, t + 4); ATT_BODY(2); WB2;   // confirms t+3
  }
  STAGE_KV(2, 29); ATT_BODY(0); WB2;       // confirms 28
  STAGE_KV(0, 30); ATT_BODY(1); WB2;       // confirms 29
  STAGE_KV(1, 31); ATT_BODY(2); WB2;       // confirms 30
  ATT_BODY(0); WB0;                        // confirms 31
  ATT_BODY(1);
#undef ATT_BODY
#undef STAGE_KV

  float il0[4], il1[4];
#pragma unroll
  for (int r = 0; r < 4; r++) {
    il0[r] = __builtin_amdgcn_rcpf(ol0[r]);
    il1[r] = __builtin_amdgcn_rcpf(ol1[r]);
  }
  const int b = bh / NH, h = bh % NH;
#pragma unroll
  for (int dt = 0; dt < 4; dt++)
#pragma unroll
    for (int r = 0; r < 4; r++) {
      const int n = q0 + 4 * g + r;
      Ab[(size_t)(b * 1024 + n) * 768 + h * 64 + dt * 16 + c15] =
          f2bf(o0[dt][r] * il0[r]);
      Ab[(size_t)(b * 1024 + n + 16) * 768 + h * 64 + dt * 16 + c15] =
          f2bf(o1[dt][r] * il1[r]);
    }
}

// ---------------- Kernel 3: output projection ----------------------------
__global__ __launch_bounds__(256, 3) void k_proj(const ushort* __restrict__ Ain,
                                                 const ushort* __restrict__ W,
                                                 const float* __restrict__ Bp,
                                                 float* __restrict__ Out) {
  __shared__ __align__(16) ushort lds[24576];
  const int id = (int)blockIdx.x;          // 384 blocks, %8==0
  const int swz = (id & 7) * 48 + (id >> 3);
  const int bx = swz % 6, by = swz / 6;
  const int m0 = by * 128, n0 = bx * 128;
  DECL_GEMM_VARS();

  ushort* A0 = lds;
  ushort* A1 = lds + 4096;
  ushort* A2 = lds + 8192;
  ushort* B0 = lds + 12288;
  ushort* B1 = lds + 16384;
  ushort* B2 = lds + 20480;

  f32x4 acc[4][4] = {};
  GEMM_PIPE(Ain, W);

#pragma unroll
  for (int nr = 0; nr < 4; nr++) {
    const int cc = n0 + wn * 64 + nr * 16 + c15;
    const float bias = Bp[cc];
#pragma unroll
    for (int mr = 0; mr < 4; mr++) {
      const int mb = m0 + wm * 64 + mr * 16 + 4 * g;
#pragma unroll
      for (int r = 0; r < 4; r++) {
        const int m = mb + r;
        Out[(size_t)m * 768 + cc] = acc[mr][nr][r] + bias;
      }
    }
  }
}

extern "C" void kernel_launch(void* const* d_in, const int* in_sizes, int n_in,
                              void* d_out, int out_size, void* d_ws, size_t ws_size,
                              hipStream_t stream) {
  const float* X  = (const float*)d_in[0];   // [8,1024,768] fp32
  const float* Wq = (const float*)d_in[1];   // [2304,768] fp32
  const float* Wp = (const float*)d_in[2];   // [768,768] fp32
  const float* Bp = (const float*)d_in[3];   // [768] fp32
  float* Out = (float*)d_out;                // [8,1024,768] fp32

  char* ws = (char*)d_ws;
  const size_t SZ = (size_t)96 * 1024 * 64 * sizeof(ushort);  // 12.58 MB
  ushort* Qb  = (ushort*)(ws);            // [96][1024][64] (scaled by QSCALE)
  ushort* Kf  = (ushort*)(ws + SZ);       // [96][32][4][64][8] fragment order
  ushort* Vf  = (ushort*)(ws + 2 * SZ);   // [96][32][4][64][8] fragment order
  ushort* Ab  = (ushort*)(ws + 3 * SZ);   // [8192][768]
  ushort* Xb  = (ushort*)(ws + 4 * SZ);   // [8192][768] bf16 of X
  ushort* Wqb = (ushort*)(ws + 5 * SZ);                  // [2304][768] permuted
  ushort* Wpb = (ushort*)(ws + 5 * SZ + 2304 * 768 * 2); // [768][768]

  k_cvt_all<<<(N4_X + N4_WQ + N4_WP) / 256, 256, 0, stream>>>(
      (const float4*)X, (const float4*)Wq, (const float4*)Wp,
      (ushort4*)Xb, (ushort4*)Wqb, (ushort4*)Wpb);

  k_qkv<<<1152, 256, 0, stream>>>(Xb, Wqb, Qb, Kf, Vf);
  k_attn<<<dim3(96, 8), 256, 0, stream>>>(Qb, Kf, Vf, Ab);
  k_proj<<<384, 256, 0, stream>>>(Ab, Wpb, Bp, Out);
}